// Round 6
// baseline (226.579 us; speedup 1.0000x reference)
//
#include <hip/hip_runtime.h>
#include <hip/hip_bf16.h>

#define N_PIX 8192
#define C_DIM 128
#define HW 4096
// exp(dot/0.1) = exp2(dot * 14.42695...); fold sqrt of that into each vector.
#define PRESCALE 3.7982825f  // sqrt(log2(e)/0.1)
#define NUM_CLASSES 4

typedef __attribute__((ext_vector_type(8))) short short8;   // 8 x bf16 (4 VGPRs)
typedef __attribute__((ext_vector_type(4))) float float4v;  // 4 x f32 acc

// ---------------- Kernel 1: L2-normalize + prescale + bf16 cast; zero pos/tot ----------------
__global__ __launch_bounds__(256) void normscale_kernel(const float* __restrict__ emb,
                                                        unsigned short* __restrict__ ebf,
                                                        float* __restrict__ pz) {
    const int tid = threadIdx.x;
    const int p16 = tid & 15;   // pixel within block
    const int g = tid >> 4;     // channel group 0..15 (8 channels each)
    const int n = blockIdx.x * 16 + p16;
    const int b = n >> 12;
    const int hw = n & (HW - 1);
    const float* base = emb + b * (C_DIM * HW) + hw;

    float v[8];
    float ss = 0.f;
#pragma unroll
    for (int i = 0; i < 8; ++i) {
        v[i] = base[(g * 8 + i) * HW];
        ss += v[i] * v[i];
    }
    ss += __shfl_xor(ss, 16, 64);
    ss += __shfl_xor(ss, 32, 64);
    __shared__ float red[4][16];
    const int wv = tid >> 6;
    if ((tid & 63) < 16) red[wv][p16] = ss;
    __syncthreads();
    float tot = red[0][p16] + red[1][p16] + red[2][p16] + red[3][p16];
    float inv = PRESCALE / fmaxf(sqrtf(tot), 1e-12f);

    unsigned short us[8];
#pragma unroll
    for (int i = 0; i < 8; ++i) {
        __hip_bfloat16 h = __float2bfloat16(v[i] * inv);
        us[i] = *reinterpret_cast<unsigned short*>(&h);
    }
    *reinterpret_cast<short8*>(ebf + n * C_DIM + g * 8) = *reinterpret_cast<short8*>(us);

    // zero pos[8192]+tot[8192] (contiguous) using the first 64 blocks
    if (blockIdx.x < 64) pz[blockIdx.x * 256 + tid] = 0.f;
}

// ---------------- Kernel 2: fused S = e e^T (prescaled), exp2, masked row sums ----------------
// Grid (64 row-blocks x 32 j-splits) = 2048 blocks. Block 256 = 4 waves, no barriers.
// Direct cached global loads for B (R5 lesson: global_load_lds staging on this
// cache-resident input exploded HBM traffic 8MB->476MB; plain loads hit L1/L2).
// Depth-2 software pipeline: load B(t+1) | MFMA(t) | epilogue(t-1) so VMEM,
// MFMA and VALU pipes overlap within one wave. ~100 VGPRs -> 4 waves/SIMD.
// __launch_bounds__(256,4): cap 128 VGPRs, no spill (R3 lesson: (256,8) spills).
__global__ __launch_bounds__(256, 4) void pairwise_kernel(const unsigned short* __restrict__ ebf,
                                                          const int* __restrict__ lab,
                                                          float* __restrict__ pos,
                                                          float* __restrict__ tot) {
    const int wave = threadIdx.x >> 6;
    const int lane = threadIdx.x & 63;
    const int quad = lane >> 4;
    const int lq = lane & 15;

    const int I0 = blockIdx.x * 128 + wave * 32;
    const int Jbase = blockIdx.y * 256;

    // A fragments: rows I0..I0+31, loaded once.
    short8 afrag[2][4];
#pragma unroll
    for (int a = 0; a < 2; ++a) {
        const unsigned short* arow = ebf + (I0 + a * 16 + lq) * C_DIM + quad * 8;
#pragma unroll
        for (int s = 0; s < 4; ++s)
            afrag[a][s] = *reinterpret_cast<const short8*>(arow + s * 32);
    }
    int lab_row[2][4];
#pragma unroll
    for (int a = 0; a < 2; ++a)
#pragma unroll
        for (int r = 0; r < 4; ++r) lab_row[a][r] = lab[I0 + a * 16 + quad * 4 + r];

    float tacc[2][4] = {};
    float pacc[2][4] = {};

    // epilogue for tile T (C/D layout: col=lq within tile, row=quad*4+r)
    auto epilogue = [&](int T, const float4v& a0, const float4v& a1, int lab_col) {
        const int J = Jbase + T * 16;
        const bool m0 = (J == I0);        // wave-uniform diagonal-tile flags
        const bool m1 = (J == I0 + 16);
#pragma unroll
        for (int r = 0; r < 4; ++r) {
            float ex = __builtin_amdgcn_exp2f(a0[r]);
            if (m0) ex = (lq == quad * 4 + r) ? 0.f : ex;
            tacc[0][r] += ex;
            pacc[0][r] += (lab_row[0][r] == lab_col) ? ex : 0.f;
        }
#pragma unroll
        for (int r = 0; r < 4; ++r) {
            float ex = __builtin_amdgcn_exp2f(a1[r]);
            if (m1) ex = (lq == quad * 4 + r) ? 0.f : ex;
            tacc[1][r] += ex;
            pacc[1][r] += (lab_row[1][r] == lab_col) ? ex : 0.f;
        }
    };

    short8 bfr[2][4];
    float4v acc[2][2];
    int labc[2];

    // prolog: tile 0
    {
        const unsigned short* brow = ebf + (Jbase + lq) * C_DIM + quad * 8;
#pragma unroll
        for (int s = 0; s < 4; ++s)
            bfr[0][s] = *reinterpret_cast<const short8*>(brow + s * 32);
        labc[0] = lab[Jbase + lq];
    }

#pragma unroll
    for (int t = 0; t < 16; ++t) {
        const int cur = t & 1, nxt = cur ^ 1;

        // (1) prefetch B fragments for tile t+1 (independent of everything below)
        if (t + 1 < 16) {
            const unsigned short* brow = ebf + (Jbase + (t + 1) * 16 + lq) * C_DIM + quad * 8;
#pragma unroll
            for (int s = 0; s < 4; ++s)
                bfr[nxt][s] = *reinterpret_cast<const short8*>(brow + s * 32);
        }

        // (2) MFMA tile t
        acc[cur][0] = float4v{0.f, 0.f, 0.f, 0.f};
        acc[cur][1] = float4v{0.f, 0.f, 0.f, 0.f};
#pragma unroll
        for (int s = 0; s < 4; ++s) {
            acc[cur][0] = __builtin_amdgcn_mfma_f32_16x16x32_bf16(afrag[0][s], bfr[cur][s], acc[cur][0], 0, 0, 0);
            acc[cur][1] = __builtin_amdgcn_mfma_f32_16x16x32_bf16(afrag[1][s], bfr[cur][s], acc[cur][1], 0, 0, 0);
        }

        // (3) epilogue of tile t-1 (VALU, overlaps the matrix pipe)
        if (t > 0) epilogue(t - 1, acc[nxt][0], acc[nxt][1], labc[nxt]);

        // label prefetch for t+1 (after epilogue consumed labc[nxt])
        if (t + 1 < 16) labc[nxt] = lab[Jbase + (t + 1) * 16 + lq];
    }
    epilogue(15, acc[1][0], acc[1][1], labc[1]);

#pragma unroll
    for (int a = 0; a < 2; ++a) {
#pragma unroll
        for (int r = 0; r < 4; ++r) {
            float t = tacc[a][r], p = pacc[a][r];
#pragma unroll
            for (int off = 1; off < 16; off <<= 1) {
                t += __shfl_xor(t, off, 64);
                p += __shfl_xor(p, off, 64);
            }
            if (lq == 0) {
                const int row = I0 + a * 16 + quad * 4 + r;
                atomicAdd(&tot[row], t);
                atomicAdd(&pos[row], p);
            }
        }
    }
}

// ---------------- Kernel 3: row losses + per-class mean of means ----------------
__global__ __launch_bounds__(1024) void finalize_kernel(const float* __restrict__ pos,
                                                        const float* __restrict__ tot,
                                                        const int* __restrict__ lab,
                                                        float* __restrict__ out) {
    const int tid = threadIdx.x;
    float ls[NUM_CLASSES] = {0.f, 0.f, 0.f, 0.f};
    float lc[NUM_CLASSES] = {0.f, 0.f, 0.f, 0.f};
#pragma unroll
    for (int it = 0; it < N_PIX / 1024; ++it) {
        const int n = it * 1024 + tid;
        float rl = logf(tot[n] + 1e-6f) - logf(pos[n]);
        int c = lab[n];
#pragma unroll
        for (int k = 0; k < NUM_CLASSES; ++k) {
            if (c == k) {
                ls[k] += rl;
                lc[k] += 1.f;
            }
        }
    }
#pragma unroll
    for (int off = 1; off < 64; off <<= 1) {
#pragma unroll
        for (int k = 0; k < NUM_CLASSES; ++k) {
            ls[k] += __shfl_xor(ls[k], off, 64);
            lc[k] += __shfl_xor(lc[k], off, 64);
        }
    }
    __shared__ float ssum[16][NUM_CLASSES];
    __shared__ float scnt[16][NUM_CLASSES];
    const int wid = tid >> 6;
    if ((tid & 63) == 0) {
#pragma unroll
        for (int k = 0; k < NUM_CLASSES; ++k) {
            ssum[wid][k] = ls[k];
            scnt[wid][k] = lc[k];
        }
    }
    __syncthreads();
    if (tid == 0) {
        float acc = 0.f;
        int present = 0;
        for (int k = 0; k < NUM_CLASSES; ++k) {
            float s = 0.f, c = 0.f;
            for (int w = 0; w < 16; ++w) {
                s += ssum[w][k];
                c += scnt[w][k];
            }
            if (c > 0.f) {
                acc += s / c;
                present++;
            }
        }
        out[0] = acc / (float)(present > 0 ? present : 1);
    }
}

extern "C" void kernel_launch(void* const* d_in, const int* in_sizes, int n_in,
                              void* d_out, int out_size, void* d_ws, size_t ws_size,
                              hipStream_t stream) {
    const float* emb = (const float*)d_in[0];  // [2,128,64,64] fp32
    const int* lab = (const int*)d_in[1];      // [2,64,64] int32
    float* out = (float*)d_out;

    unsigned short* ebf = (unsigned short*)d_ws;             // [8192][128] bf16 = 2 MiB
    float* pos = (float*)((char*)d_ws + N_PIX * C_DIM * 2);  // [8192] f32
    float* tot = pos + N_PIX;                                // [8192] f32 (contiguous)

    normscale_kernel<<<N_PIX / 16, 256, 0, stream>>>(emb, ebf, pos);

    dim3 grid(N_PIX / 128, 32);  // 2048 blocks
    pairwise_kernel<<<grid, 256, 0, stream>>>(ebf, lab, pos, tot);

    finalize_kernel<<<1, 1024, 0, stream>>>(pos, tot, lab, out);
}

// Round 7
// 97.223 us; speedup vs baseline: 2.3305x; 2.3305x over previous
//
#include <hip/hip_runtime.h>
#include <hip/hip_bf16.h>

#define N_PIX 8192
#define C_DIM 128
#define HW 4096
// exp(dot/0.1) = exp2(dot * 14.42695...); fold sqrt of that into each vector.
#define PRESCALE 3.7982825f  // sqrt(log2(e)/0.1)
#define NUM_CLASSES 4

typedef __attribute__((ext_vector_type(8))) short short8;   // 8 x bf16 (4 VGPRs)
typedef __attribute__((ext_vector_type(4))) float float4v;  // 4 x f32 acc

// Fragment-linear layout: ebfT[((T*4 + s)*64 + lane)*8 + j] = e[T*16 + lq][s*32 + quad*8 + j]
// where lane = quad*16 + lq. A wave's fragment load for (tile T, k-block s) is then
// base + lane*16B: one coalesced 1KB global_load_dwordx4 touching 8 sequential lines
// (vs R4's 16-line gather -- the structural 5-6x latency wall of R1/R2/R4).

// ---------------- Kernel 1: L2-normalize + prescale + bf16 cast into ebfT; zero pos/tot ----------------
// 512 blocks x 256 threads; block bx covers pixels bx*16..+15 == exactly tile T=bx.
__global__ __launch_bounds__(256) void normscale_kernel(const float* __restrict__ emb,
                                                        unsigned short* __restrict__ ebfT,
                                                        float* __restrict__ pz) {
    const int tid = threadIdx.x;
    const int p16 = tid & 15;   // pixel within tile (lq)
    const int g = tid >> 4;     // channel group 0..15 (8 channels each)
    const int n = blockIdx.x * 16 + p16;
    const int b = n >> 12;
    const int hw = n & (HW - 1);
    const float* base = emb + b * (C_DIM * HW) + hw;

    float v[8];
    float ss = 0.f;
#pragma unroll
    for (int i = 0; i < 8; ++i) {
        v[i] = base[(g * 8 + i) * HW];
        ss += v[i] * v[i];
    }
    ss += __shfl_xor(ss, 16, 64);
    ss += __shfl_xor(ss, 32, 64);
    __shared__ float red[4][16];
    const int wv = tid >> 6;
    if ((tid & 63) < 16) red[wv][p16] = ss;
    __syncthreads();
    float tot = red[0][p16] + red[1][p16] + red[2][p16] + red[3][p16];
    float inv = PRESCALE / fmaxf(sqrtf(tot), 1e-12f);

    unsigned short us[8];
#pragma unroll
    for (int i = 0; i < 8; ++i) {
        __hip_bfloat16 h = __float2bfloat16(v[i] * inv);
        us[i] = *reinterpret_cast<unsigned short*>(&h);
    }
    // channels g*8..g*8+7 -> s = g>>2, quad = g&3; dest = ((bx*4+s)*64 + quad*16 + p16)*8
    const int s = g >> 2, quad = g & 3;
    unsigned short* dst = ebfT + (((blockIdx.x * 4 + s) * 64 + quad * 16 + p16) << 3);
    *reinterpret_cast<short8*>(dst) = *reinterpret_cast<short8*>(us);

    // zero pos[8192]+tot[8192] (contiguous) using the first 64 blocks
    if (blockIdx.x < 64) pz[blockIdx.x * 256 + tid] = 0.f;
}

// ---------------- Kernel 2: fused S = e e^T (prescaled), exp2, masked row sums ----------------
// Grid (64 row-blocks x 32 j-splits) = 2048 blocks. Block 256 = 4 waves, no barriers, no LDS.
// R4 structure + fragment-linear loads. Lessons baked in:
//   R3: __launch_bounds__(256,8) spills -> keep (256,4).
//   R5: global_load_lds staging explodes HBM traffic on cache-resident input -> plain loads.
//   R6: lambda-by-ref + state arrays -> scratch demotion -> macros, flat scalars only.
__global__ __launch_bounds__(256, 4) void pairwise_kernel(const unsigned short* __restrict__ ebfT,
                                                          const int* __restrict__ lab,
                                                          float* __restrict__ pos,
                                                          float* __restrict__ tot) {
    const int wave = threadIdx.x >> 6;
    const int lane = threadIdx.x & 63;
    const int quad = lane >> 4;
    const int lq = lane & 15;

    const int I0 = blockIdx.x * 128 + wave * 32;
    const int Jbase = blockIdx.y * 256;

    // A fragments: tiles I0/16 and I0/16+1, coalesced (base + lane*16B).
    short8 afrag[2][4];
#pragma unroll
    for (int a = 0; a < 2; ++a) {
        const unsigned short* ab = ebfT + ((((I0 >> 4) + a) * 4) * 64 + lane) * 8;
#pragma unroll
        for (int s = 0; s < 4; ++s)
            afrag[a][s] = *reinterpret_cast<const short8*>(ab + s * 512);
    }
    int lab_row[2][4];
#pragma unroll
    for (int a = 0; a < 2; ++a)
#pragma unroll
        for (int r = 0; r < 4; ++r) lab_row[a][r] = lab[I0 + a * 16 + quad * 4 + r];

    float tacc[2][4] = {};
    float pacc[2][4] = {};

#define EPILOGUE(A, ACC, MASKED)                                            \
    {                                                                       \
        _Pragma("unroll") for (int r = 0; r < 4; ++r) {                     \
            float ex = __builtin_amdgcn_exp2f(ACC[r]);                      \
            if (MASKED) ex = (lq == quad * 4 + r) ? 0.f : ex;               \
            tacc[A][r] += ex;                                               \
            pacc[A][r] += (lab_row[A][r] == lab_col) ? ex : 0.f;            \
        }                                                                   \
    }

    // B fragment stream: tile t at bbase + t*4KB + s*1KB, all coalesced.
    const unsigned short* bbase = ebfT + ((Jbase >> 4) * 4 * 64 + lane) * 8;

    for (int t = 0; t < 16; ++t) {
        const int J = Jbase + t * 16;
        const int lab_col = lab[J + lq];
        const unsigned short* bt = bbase + t * 2048;
        short8 bfrag[4];
#pragma unroll
        for (int s = 0; s < 4; ++s)
            bfrag[s] = *reinterpret_cast<const short8*>(bt + s * 512);

        float4v acc0 = {0.f, 0.f, 0.f, 0.f};
        float4v acc1 = {0.f, 0.f, 0.f, 0.f};
#pragma unroll
        for (int s = 0; s < 4; ++s) {
            acc0 = __builtin_amdgcn_mfma_f32_16x16x32_bf16(afrag[0][s], bfrag[s], acc0, 0, 0, 0);
            acc1 = __builtin_amdgcn_mfma_f32_16x16x32_bf16(afrag[1][s], bfrag[s], acc1, 0, 0, 0);
        }
        // diagonal only when the 16-col tile coincides with a 16-row set (wave-uniform)
        if (J == I0) EPILOGUE(0, acc0, true) else EPILOGUE(0, acc0, false);
        if (J == I0 + 16) EPILOGUE(1, acc1, true) else EPILOGUE(1, acc1, false);
    }
#undef EPILOGUE

#pragma unroll
    for (int a = 0; a < 2; ++a) {
#pragma unroll
        for (int r = 0; r < 4; ++r) {
            float t = tacc[a][r], p = pacc[a][r];
#pragma unroll
            for (int off = 1; off < 16; off <<= 1) {
                t += __shfl_xor(t, off, 64);
                p += __shfl_xor(p, off, 64);
            }
            if (lq == 0) {
                const int row = I0 + a * 16 + quad * 4 + r;
                atomicAdd(&tot[row], t);
                atomicAdd(&pos[row], p);
            }
        }
    }
}

// ---------------- Kernel 3: row losses + per-class mean of means ----------------
__global__ __launch_bounds__(1024) void finalize_kernel(const float* __restrict__ pos,
                                                        const float* __restrict__ tot,
                                                        const int* __restrict__ lab,
                                                        float* __restrict__ out) {
    const int tid = threadIdx.x;
    float ls[NUM_CLASSES] = {0.f, 0.f, 0.f, 0.f};
    float lc[NUM_CLASSES] = {0.f, 0.f, 0.f, 0.f};
#pragma unroll
    for (int it = 0; it < N_PIX / 1024; ++it) {
        const int n = it * 1024 + tid;
        float rl = logf(tot[n] + 1e-6f) - logf(pos[n]);
        int c = lab[n];
#pragma unroll
        for (int k = 0; k < NUM_CLASSES; ++k) {
            if (c == k) {
                ls[k] += rl;
                lc[k] += 1.f;
            }
        }
    }
#pragma unroll
    for (int off = 1; off < 64; off <<= 1) {
#pragma unroll
        for (int k = 0; k < NUM_CLASSES; ++k) {
            ls[k] += __shfl_xor(ls[k], off, 64);
            lc[k] += __shfl_xor(lc[k], off, 64);
        }
    }
    __shared__ float ssum[16][NUM_CLASSES];
    __shared__ float scnt[16][NUM_CLASSES];
    const int wid = tid >> 6;
    if ((tid & 63) == 0) {
#pragma unroll
        for (int k = 0; k < NUM_CLASSES; ++k) {
            ssum[wid][k] = ls[k];
            scnt[wid][k] = lc[k];
        }
    }
    __syncthreads();
    if (tid == 0) {
        float acc = 0.f;
        int present = 0;
        for (int k = 0; k < NUM_CLASSES; ++k) {
            float s = 0.f, c = 0.f;
            for (int w = 0; w < 16; ++w) {
                s += ssum[w][k];
                c += scnt[w][k];
            }
            if (c > 0.f) {
                acc += s / c;
                present++;
            }
        }
        out[0] = acc / (float)(present > 0 ? present : 1);
    }
}

extern "C" void kernel_launch(void* const* d_in, const int* in_sizes, int n_in,
                              void* d_out, int out_size, void* d_ws, size_t ws_size,
                              hipStream_t stream) {
    const float* emb = (const float*)d_in[0];  // [2,128,64,64] fp32
    const int* lab = (const int*)d_in[1];      // [2,64,64] int32
    float* out = (float*)d_out;

    unsigned short* ebfT = (unsigned short*)d_ws;            // [512 tiles][4][64][8] bf16 = 2 MiB
    float* pos = (float*)((char*)d_ws + N_PIX * C_DIM * 2);  // [8192] f32
    float* tot = pos + N_PIX;                                // [8192] f32 (contiguous)

    normscale_kernel<<<N_PIX / 16, 256, 0, stream>>>(emb, ebfT, pos);

    dim3 grid(N_PIX / 128, 32);  // 2048 blocks
    pairwise_kernel<<<grid, 256, 0, stream>>>(ebfT, lab, pos, tot);

    finalize_kernel<<<1, 1024, 0, stream>>>(pos, tot, lab, out);
}